// Round 17
// baseline (210.030 us; speedup 1.0000x reference)
//
#include <hip/hip_runtime.h>
#include <stdint.h>
#include <math.h>

typedef __attribute__((ext_vector_type(8))) __bf16 bf16x8;
typedef __attribute__((ext_vector_type(4))) __bf16 bf16x4;
typedef __attribute__((ext_vector_type(4))) float f32x4;

// -------- fragment-major tiled layout for totalbf --------
// 16-row x 32-col fragment blocks in MFMA order. Element (row, o):
//   row-block = row>>4 (4096 elems), col-block = o>>5 (512 elems),
//   inner = q<<7 | n16<<3 | e  with q=(o>>3)&3, n16=row&15, e=o&7.
// Lane l = q*16+n16 owns the 8 elems at +l*8: one 16x32 fragment = ONE
// coalesced 1KB wave-load (dwordx4/lane). Verified R11.
__device__ __forceinline__ size_t tbidx(int row, int o) {
  return ((size_t)(row >> 4) << 12) + ((o >> 5) << 9) +
         (((o >> 3) & 3) << 7) + ((row & 15) << 3) + (o & 7);
}

// ---------------- outs GEMM: C[m][n] = sum_k x[m][k] * Wflat[n][k] + bias[n] ----
// R15-proven config (best total 138.9): 64x32 tiles, BK=64, grid (16,64) =
// 1024 blocks = 4 blocks/CU. Reg-staged bf16, XOR swizzle,
// prefetch-after-barrier; fragment-major store. Block (0,0) zero-inits.
__global__ __launch_bounds__(256) void k_outs(const float* __restrict__ x,
                                              const float* __restrict__ W,
                                              const float* __restrict__ bias,
                                              __bf16* __restrict__ totalbf,
                                              float* __restrict__ colsum,
                                              float* __restrict__ scal,
                                              float* __restrict__ out) {
  __shared__ __bf16 As[64][64];   // M-rows x K
  __shared__ __bf16 Bs[32][64];   // N-rows x K
  const int bj = blockIdx.x;   // 0..15 (N tiles of 32)
  const int bi = blockIdx.y;   // 0..63 (M tiles of 64)
  const int t = threadIdx.x;
  if (bj == 0 && bi == 0) {
    colsum[t] = 0.f;
    if (t < 8) scal[t] = 0.f;
    if (t == 0) out[1048576] = 0.f;
  }
  const int wid = t >> 6, lane = t & 63;
  const int wr = wid >> 1, wc = wid & 1;
  const int n16 = lane & 15, q = lane >> 4;
  const int sx = (n16 & 7) << 3;        // read-side swizzle (element units)
  const int erow = t >> 4;              // 0..15 (+p*16)
  const int c4 = (t & 15) << 2;         // 0..60

  f32x4 acc[2];
  f32x4 zero = {0.f, 0.f, 0.f, 0.f};
  acc[0] = zero; acc[1] = zero;

  const int arow0 = bi * 64, brow0 = bj * 32;

  float4 ra[4], rb[2];
#pragma unroll
  for (int p = 0; p < 4; ++p)
    ra[p] = *(const float4*)(x + (size_t)(arow0 + p * 16 + erow) * 512 + c4);
#pragma unroll
  for (int p = 0; p < 2; ++p)
    rb[p] = *(const float4*)(W + (size_t)(brow0 + p * 16 + erow) * 512 + c4);

  for (int kc = 0; kc < 512; kc += 64) {
#pragma unroll
    for (int p = 0; p < 4; ++p) {
      int row = p * 16 + erow;
      int col = c4 ^ ((row & 7) << 3);
      float4 va = ra[p];
      bf16x4 ba = {(__bf16)va.x, (__bf16)va.y, (__bf16)va.z, (__bf16)va.w};
      *(bf16x4*)&As[row][col] = ba;
    }
#pragma unroll
    for (int p = 0; p < 2; ++p) {
      int row = p * 16 + erow;
      int col = c4 ^ ((row & 7) << 3);
      float4 vb = rb[p];
      bf16x4 bb = {(__bf16)vb.x, (__bf16)vb.y, (__bf16)vb.z, (__bf16)vb.w};
      *(bf16x4*)&Bs[row][col] = bb;
    }
    __syncthreads();
    // issue next-tile global loads AFTER the barrier: they fly under the MFMAs
    if (kc < 448) {
#pragma unroll
      for (int p = 0; p < 4; ++p)
        ra[p] = *(const float4*)(x + (size_t)(arow0 + p * 16 + erow) * 512 + kc + 64 + c4);
#pragma unroll
      for (int p = 0; p < 2; ++p)
        rb[p] = *(const float4*)(W + (size_t)(brow0 + p * 16 + erow) * 512 + kc + 64 + c4);
    }
#pragma unroll
    for (int ks = 0; ks < 2; ++ks) {
      bf16x8 af[2], bfr;
#pragma unroll
      for (int f = 0; f < 2; ++f)
        af[f] = *(const bf16x8*)&As[wr * 32 + f * 16 + n16][(ks * 32 + q * 8) ^ sx];
      bfr = *(const bf16x8*)&Bs[wc * 16 + n16][(ks * 32 + q * 8) ^ sx];
      for (int fr = 0; fr < 2; ++fr)
        acc[fr] = __builtin_amdgcn_mfma_f32_16x16x32_bf16(af[fr], bfr, acc[fr], 0, 0, 0);
    }
    __syncthreads();
  }

  {
    int n_g = bj * 32 + wc * 16 + n16;   // 0..511
    float bv = bias[n_g];
    int l = n_g >> 8, o = n_g & 255;
    for (int fr = 0; fr < 2; ++fr) {
      for (int r = 0; r < 4; ++r) {
        int m_g = bi * 64 + wr * 32 + fr * 16 + q * 4 + r;
        float v = acc[fr][r] + bv;
        totalbf[tbidx(l * 4096 + m_g, o)] = (__bf16)v;
      }
    }
  }
}

// ------- fused: gates + sq + colsum + combine + bandwidth finalize ------------
// R14-proven: 128 blocks, 8 rows/wave ILP, sigmoid gates, atomic colsum
// (32K RMWs fine), last-block bandwidth finalize. UNCHANGED.
__global__ __launch_bounds__(256) void k_sqc(const __bf16* __restrict__ tot,
                                             const float* __restrict__ x,
                                             const float* __restrict__ Waux,
                                             const float* __restrict__ baux,
                                             float* __restrict__ sq,
                                             float* __restrict__ colsum,
                                             float* __restrict__ scal,
                                             float* __restrict__ out) {
  __shared__ float lcol[4][256];
  __shared__ float wsq[4];
  __shared__ unsigned int isLast;
  const int t = threadIdx.x;
  const int wave = t >> 6, lane = t & 63;

  // ---- gates: d = x.(w0-w1) + (b0-b1); g0 = sigmoid(d), g1 = 1-g0 ----
  const float4* wa = (const float4*)(Waux);          // row 0: 128 float4
  const float4* wb = (const float4*)(Waux + 512);    // row 1
  float4 wa0 = wa[lane * 2], wa1 = wa[lane * 2 + 1];
  float4 wb0 = wb[lane * 2], wb1 = wb[lane * 2 + 1];
  float4 wd0 = {wa0.x - wb0.x, wa0.y - wb0.y, wa0.z - wb0.z, wa0.w - wb0.w};
  float4 wd1 = {wa1.x - wb1.x, wa1.y - wb1.y, wa1.z - wb1.z, wa1.w - wb1.w};
  const float bd = baux[0] - baux[1];
  float g0[8], g1[8];
#pragma unroll
  for (int it = 0; it < 8; ++it) {
    int m = blockIdx.x * 32 + wave * 8 + it;
    const float4* xr = (const float4*)(x + (size_t)m * 512);
    float4 x0 = xr[lane * 2], x1 = xr[lane * 2 + 1];
    float d = x0.x * wd0.x + x0.y * wd0.y + x0.z * wd0.z + x0.w * wd0.w
            + x1.x * wd1.x + x1.y * wd1.y + x1.z * wd1.z + x1.w * wd1.w;
    for (int off = 32; off; off >>= 1) d += __shfl_xor(d, off, 64);
    d += bd;
    float g = 1.f / (1.f + __expf(-d));
    g0[it] = g;
    g1[it] = 1.f - g;
  }

  // ---- sq + colsum + combine ----
  float c0 = 0.f, c1 = 0.f, c2 = 0.f, c3 = 0.f;
  float bsq = 0.f;
#pragma unroll
  for (int it = 0; it < 8; ++it) {
    int m = blockIdx.x * 32 + wave * 8 + it;      // 0..4095
    bf16x4 v0 = *(const bf16x4*)(tot + tbidx(m, lane * 4));
    bf16x4 v1 = *(const bf16x4*)(tot + tbidx(4096 + m, lane * 4));
    float f00 = v0[0], f01 = v0[1], f02 = v0[2], f03 = v0[3];
    float f10 = v1[0], f11 = v1[1], f12 = v1[2], f13 = v1[3];
    float s0 = f00 * f00 + f01 * f01 + f02 * f02 + f03 * f03;
    float s1 = f10 * f10 + f11 * f11 + f12 * f12 + f13 * f13;
    for (int off = 32; off; off >>= 1) {
      s0 += __shfl_down(s0, off, 64);
      s1 += __shfl_down(s1, off, 64);
    }
    if (lane == 0) { sq[m] = s0; sq[4096 + m] = s1; bsq += s0 + s1; }
    c0 += f00 + f10; c1 += f01 + f11; c2 += f02 + f12; c3 += f03 + f13;
    float4 r;
    r.x = g0[it] * f00 + g1[it] * f10;
    r.y = g0[it] * f01 + g1[it] * f11;
    r.z = g0[it] * f02 + g1[it] * f12;
    r.w = g0[it] * f03 + g1[it] * f13;
    *(float4*)(out + (size_t)m * 256 + lane * 4) = r;
  }
  lcol[wave][lane * 4 + 0] = c0;
  lcol[wave][lane * 4 + 1] = c1;
  lcol[wave][lane * 4 + 2] = c2;
  lcol[wave][lane * 4 + 3] = c3;
  if (lane == 0) wsq[wave] = bsq;
  __syncthreads();
  float s2 = lcol[0][t] + lcol[1][t] + lcol[2][t] + lcol[3][t];
  atomicAdd(&colsum[t], s2);
  if (t == 0) atomicAdd(&scal[4], wsq[0] + wsq[1] + wsq[2] + wsq[3]);
  __threadfence();
  if (t == 0) {
    unsigned int c = atomicAdd((unsigned int*)(scal + 5), 1u);
    isLast = (c == 127u) ? 1u : 0u;
  }
  __syncthreads();
  if (isLast) {
    __threadfence();
    float cv = atomicAdd(&colsum[t], 0.0f);      // coherent read
    lcol[0][t] = cv * cv;
    __syncthreads();
    for (int off = 128; off; off >>= 1) {
      if (t < off) lcol[0][t] += lcol[0][t + off];
      __syncthreads();
    }
    if (t == 0) {
      float sumsq = atomicAdd(&scal[4], 0.0f);
      double sumdist = 2.0 * 8192.0 * (double)sumsq - 2.0 * (double)lcol[0][0];
      double bw = sumdist / (8192.0 * 8192.0 - 8192.0) / 4.0;  // / KERNEL_MUL^(5//2)
      scal[1] = (float)(1.4426950408889634 / (bw * 16.0));     // g4 * log2(e)
      scal[2] = (float)bw;
    }
  }
}

// ---------------- Gram tiles + fused multi-bandwidth kernel sum ---------------
// R17: 64x64 tiles (was 128x128). R14-R16 counters show gram latency-bound at
// ~2 resident waves/SIMD (VGPR=100 from acc[4][4]=64 regs; Occupancy 15-22%).
// Quartering the tile: acc[2][2]=16 regs + 2-deep pipeline => ~60-75 VGPR,
// grid 8256 (=8x1032, XCD-bijective) = 32 blocks/CU pressure => 2-4x resident
// waves to cover L2 latency. Panel traffic doubles (266->528 MB L2, floor
// ~15us << 43.7). Same fragment-major coalesced loads, same even/odd
// register pipeline, same fire-and-forget scaled atomic.
__global__ __launch_bounds__(256) void k_gram(const __bf16* __restrict__ tot,
                                              const float* __restrict__ sq,
                                              const float* __restrict__ scal,
                                              float* __restrict__ out) {
  const int b = blockIdx.x;                    // 0..8255
  const int nid = (b & 7) * 1032 + (b >> 3);   // XCD-chunked, bijective (8256=8*1032)
  int ti = (int)((257.0 - sqrt(257.0 * 257.0 - 8.0 * (double)nid)) * 0.5);
  while (128 * ti - ti * (ti - 1) / 2 > nid) --ti;
  while (128 * (ti + 1) - (ti + 1) * ti / 2 <= nid) ++ti;
  const int tj = ti + (nid - (128 * ti - ti * (ti - 1) / 2));

  __shared__ float sqi[64], sqj[64];
  __shared__ float wred[4];
  const int t = threadIdx.x;
  const int wid = t >> 6, lane = t & 63;
  const int wr = wid >> 1, wc = wid & 1;
  const int n16 = lane & 15, q = lane >> 4;

  const float g = scal[1];           // log2e / (bw*16)
  if (t < 64) sqi[t] = sq[ti * 64 + t] * g;            // pre-scaled by g
  else if (t < 128) sqj[t - 64] = sq[tj * 64 + (t - 64)] * g;

  f32x4 acc[2][2];
  f32x4 zero = {0.f, 0.f, 0.f, 0.f};
  for (int i = 0; i < 2; ++i)
    for (int j = 0; j < 2; ++j) acc[i][j] = zero;

  // fragment bases: A-frag f covers rows ti*64+wr*32+f*16..+16 — row-block
  // (ti*4+wr*2+f); lane l's 16B slice at +l*8 elems; col-block ks at +ks*512.
  const __bf16* pA = tot + ((size_t)(ti * 4 + wr * 2) << 12) + lane * 8;
  const __bf16* pB = tot + ((size_t)(tj * 4 + wc * 2) << 12) + lane * 8;

  bf16x8 aE[2], bE[2], aO[2], bO[2];   // even/odd ks fragment sets
#pragma unroll
  for (int f = 0; f < 2; ++f) {
    aE[f] = *(const bf16x8*)(pA + ((size_t)f << 12));
    bE[f] = *(const bf16x8*)(pB + ((size_t)f << 12));
  }
#pragma unroll
  for (int ks = 0; ks < 8; ++ks) {
    // prefetch ks+1 into the other set (in flight during this ks's MFMAs)
    if (ks < 7) {
      if ((ks & 1) == 0) {
#pragma unroll
        for (int f = 0; f < 2; ++f) {
          aO[f] = *(const bf16x8*)(pA + ((size_t)f << 12) + ((size_t)(ks + 1) << 9));
          bO[f] = *(const bf16x8*)(pB + ((size_t)f << 12) + ((size_t)(ks + 1) << 9));
        }
      } else {
#pragma unroll
        for (int f = 0; f < 2; ++f) {
          aE[f] = *(const bf16x8*)(pA + ((size_t)f << 12) + ((size_t)(ks + 1) << 9));
          bE[f] = *(const bf16x8*)(pB + ((size_t)f << 12) + ((size_t)(ks + 1) << 9));
        }
      }
    }
    if ((ks & 1) == 0) {
      for (int fr = 0; fr < 2; ++fr)
        for (int fc = 0; fc < 2; ++fc)
          acc[fr][fc] = __builtin_amdgcn_mfma_f32_16x16x32_bf16(aE[fr], bE[fc], acc[fr][fc], 0, 0, 0);
    } else {
      for (int fr = 0; fr < 2; ++fr)
        for (int fc = 0; fc < 2; ++fc)
          acc[fr][fc] = __builtin_amdgcn_mfma_f32_16x16x32_bf16(aO[fr], bO[fc], acc[fr][fc], 0, 0, 0);
    }
  }

  __syncthreads();   // publish sqi/sqj (cross-wave)

  // epilogue: arg = 2g*acc - (g*si + g*sj); ksum = u+u2+u4+u8+u16, u=exp2(arg)
  const float twog = 2.f * g;
  float lsum = 0.f;
  for (int fr = 0; fr < 2; ++fr) {
    for (int r = 0; r < 4; ++r) {
      float gsi = sqi[wr * 32 + fr * 16 + q * 4 + r];
      for (int fc = 0; fc < 2; ++fc) {
        float gsj = sqj[wc * 32 + fc * 16 + n16];
        float u = exp2f(fmaf(twog, acc[fr][fc][r], -(gsi + gsj)));
        float u2 = u * u, u4 = u2 * u2, u8 = u4 * u4;
        float s1 = fmaf(u8, u8, u8);           // u16 + u8
        lsum += (u + u2) + (u4 + s1);
      }
    }
  }
  for (int off = 32; off; off >>= 1) lsum += __shfl_down(lsum, off, 64);
  if (lane == 0) wred[wid] = lsum;
  __syncthreads();
  if (t == 0) {
    float blocksum = wred[0] + wred[1] + wred[2] + wred[3];
    float sgn = ((ti < 64) == (tj < 64)) ? 1.f : -1.f;
    float wgt = (ti == tj) ? sgn : 2.f * sgn;
    // final scale folded in: out[1048576] = -S/2^24, accumulated directly
    atomicAdd(out + 1048576, wgt * blocksum * (-1.f / 16777216.f));
  }
}

extern "C" void kernel_launch(void* const* d_in, const int* in_sizes, int n_in,
                              void* d_out, int out_size, void* d_ws, size_t ws_size,
                              hipStream_t stream) {
  const float* x    = (const float*)d_in[0];
  const float* Waux = (const float*)d_in[1];
  const float* baux = (const float*)d_in[2];
  const float* W    = (const float*)d_in[3];
  const float* bias = (const float*)d_in[4];
  float* out = (float*)d_out;

  char* ws = (char*)d_ws;
  __bf16* totalbf = (__bf16*)ws;                    // 8192*256*2 = 4,194,304 B (tiled)
  float* sq      = (float*)(ws + 4194304);          // 8192 f32
  float* colsum  = (float*)(ws + 4227072);          // 256 f32
  float* scal    = (float*)(ws + 4228096);          // [1]=g4l2 [2]=bw [4]=sumsq [5]=cnt

  k_outs<<<dim3(16, 64), 256, 0, stream>>>(x, W, bias, totalbf, colsum, scal, out);
  k_sqc<<<128, 256, 0, stream>>>(totalbf, x, Waux, baux, sq, colsum, scal, out);
  k_gram<<<8256, 256, 0, stream>>>(totalbf, sq, scal, out);
}

// Round 18
// 139.391 us; speedup vs baseline: 1.5068x; 1.5068x over previous
//
#include <hip/hip_runtime.h>
#include <stdint.h>
#include <math.h>

typedef __attribute__((ext_vector_type(8))) __bf16 bf16x8;
typedef __attribute__((ext_vector_type(4))) __bf16 bf16x4;
typedef __attribute__((ext_vector_type(4))) float f32x4;

// -------- fragment-major tiled layout for totalbf --------
// 16-row x 32-col fragment blocks in MFMA order. Element (row, o):
//   row-block = row>>4 (4096 elems), col-block = o>>5 (512 elems),
//   inner = q<<7 | n16<<3 | e  with q=(o>>3)&3, n16=row&15, e=o&7.
// Lane l = q*16+n16 owns the 8 elems at +l*8: one 16x32 fragment = ONE
// coalesced 1KB wave-load (dwordx4/lane). Verified R11.
__device__ __forceinline__ size_t tbidx(int row, int o) {
  return ((size_t)(row >> 4) << 12) + ((o >> 5) << 9) +
         (((o >> 3) & 3) << 7) + ((row & 15) << 3) + (o & 7);
}

// ---------------- outs GEMM: C[m][n] = sum_k x[m][k] * Wflat[n][k] + bias[n] ----
// R15-proven (session-best total 138.9): 64x32 tiles, BK=64, grid (16,64) =
// 1024 blocks = 4 blocks/CU. Measured-best of {64x64/BK64, 64x32/BK64,
// 64x32/BK128, fp32-DMA-dbuf}. Reg-staged bf16, XOR swizzle,
// prefetch-after-barrier; fragment-major store. Block (0,0) zero-inits.
__global__ __launch_bounds__(256) void k_outs(const float* __restrict__ x,
                                              const float* __restrict__ W,
                                              const float* __restrict__ bias,
                                              __bf16* __restrict__ totalbf,
                                              float* __restrict__ colsum,
                                              float* __restrict__ scal,
                                              float* __restrict__ out) {
  __shared__ __bf16 As[64][64];   // M-rows x K
  __shared__ __bf16 Bs[32][64];   // N-rows x K
  const int bj = blockIdx.x;   // 0..15 (N tiles of 32)
  const int bi = blockIdx.y;   // 0..63 (M tiles of 64)
  const int t = threadIdx.x;
  if (bj == 0 && bi == 0) {
    colsum[t] = 0.f;
    if (t < 8) scal[t] = 0.f;
    if (t == 0) out[1048576] = 0.f;
  }
  const int wid = t >> 6, lane = t & 63;
  const int wr = wid >> 1, wc = wid & 1;
  const int n16 = lane & 15, q = lane >> 4;
  const int sx = (n16 & 7) << 3;        // read-side swizzle (element units)
  const int erow = t >> 4;              // 0..15 (+p*16)
  const int c4 = (t & 15) << 2;         // 0..60

  f32x4 acc[2];
  f32x4 zero = {0.f, 0.f, 0.f, 0.f};
  acc[0] = zero; acc[1] = zero;

  const int arow0 = bi * 64, brow0 = bj * 32;

  float4 ra[4], rb[2];
#pragma unroll
  for (int p = 0; p < 4; ++p)
    ra[p] = *(const float4*)(x + (size_t)(arow0 + p * 16 + erow) * 512 + c4);
#pragma unroll
  for (int p = 0; p < 2; ++p)
    rb[p] = *(const float4*)(W + (size_t)(brow0 + p * 16 + erow) * 512 + c4);

  for (int kc = 0; kc < 512; kc += 64) {
#pragma unroll
    for (int p = 0; p < 4; ++p) {
      int row = p * 16 + erow;
      int col = c4 ^ ((row & 7) << 3);
      float4 va = ra[p];
      bf16x4 ba = {(__bf16)va.x, (__bf16)va.y, (__bf16)va.z, (__bf16)va.w};
      *(bf16x4*)&As[row][col] = ba;
    }
#pragma unroll
    for (int p = 0; p < 2; ++p) {
      int row = p * 16 + erow;
      int col = c4 ^ ((row & 7) << 3);
      float4 vb = rb[p];
      bf16x4 bb = {(__bf16)vb.x, (__bf16)vb.y, (__bf16)vb.z, (__bf16)vb.w};
      *(bf16x4*)&Bs[row][col] = bb;
    }
    __syncthreads();
    // issue next-tile global loads AFTER the barrier: they fly under the MFMAs
    if (kc < 448) {
#pragma unroll
      for (int p = 0; p < 4; ++p)
        ra[p] = *(const float4*)(x + (size_t)(arow0 + p * 16 + erow) * 512 + kc + 64 + c4);
#pragma unroll
      for (int p = 0; p < 2; ++p)
        rb[p] = *(const float4*)(W + (size_t)(brow0 + p * 16 + erow) * 512 + kc + 64 + c4);
    }
#pragma unroll
    for (int ks = 0; ks < 2; ++ks) {
      bf16x8 af[2], bfr;
#pragma unroll
      for (int f = 0; f < 2; ++f)
        af[f] = *(const bf16x8*)&As[wr * 32 + f * 16 + n16][(ks * 32 + q * 8) ^ sx];
      bfr = *(const bf16x8*)&Bs[wc * 16 + n16][(ks * 32 + q * 8) ^ sx];
      for (int fr = 0; fr < 2; ++fr)
        acc[fr] = __builtin_amdgcn_mfma_f32_16x16x32_bf16(af[fr], bfr, acc[fr], 0, 0, 0);
    }
    __syncthreads();
  }

  {
    int n_g = bj * 32 + wc * 16 + n16;   // 0..511
    float bv = bias[n_g];
    int l = n_g >> 8, o = n_g & 255;
    for (int fr = 0; fr < 2; ++fr) {
      for (int r = 0; r < 4; ++r) {
        int m_g = bi * 64 + wr * 32 + fr * 16 + q * 4 + r;
        float v = acc[fr][r] + bv;
        totalbf[tbidx(l * 4096 + m_g, o)] = (__bf16)v;
      }
    }
  }
}

// ------- fused: gates + sq + colsum + combine + bandwidth finalize ------------
// R14-proven: 128 blocks, 8 rows/wave ILP, sigmoid gates (softmax-of-2 ==
// sigmoid of logit difference), atomic colsum (32K RMWs fine), last-block
// bandwidth finalize. UNCHANGED.
__global__ __launch_bounds__(256) void k_sqc(const __bf16* __restrict__ tot,
                                             const float* __restrict__ x,
                                             const float* __restrict__ Waux,
                                             const float* __restrict__ baux,
                                             float* __restrict__ sq,
                                             float* __restrict__ colsum,
                                             float* __restrict__ scal,
                                             float* __restrict__ out) {
  __shared__ float lcol[4][256];
  __shared__ float wsq[4];
  __shared__ unsigned int isLast;
  const int t = threadIdx.x;
  const int wave = t >> 6, lane = t & 63;

  // ---- gates: d = x.(w0-w1) + (b0-b1); g0 = sigmoid(d), g1 = 1-g0 ----
  const float4* wa = (const float4*)(Waux);          // row 0: 128 float4
  const float4* wb = (const float4*)(Waux + 512);    // row 1
  float4 wa0 = wa[lane * 2], wa1 = wa[lane * 2 + 1];
  float4 wb0 = wb[lane * 2], wb1 = wb[lane * 2 + 1];
  float4 wd0 = {wa0.x - wb0.x, wa0.y - wb0.y, wa0.z - wb0.z, wa0.w - wb0.w};
  float4 wd1 = {wa1.x - wb1.x, wa1.y - wb1.y, wa1.z - wb1.z, wa1.w - wb1.w};
  const float bd = baux[0] - baux[1];
  float g0[8], g1[8];
#pragma unroll
  for (int it = 0; it < 8; ++it) {
    int m = blockIdx.x * 32 + wave * 8 + it;
    const float4* xr = (const float4*)(x + (size_t)m * 512);
    float4 x0 = xr[lane * 2], x1 = xr[lane * 2 + 1];
    float d = x0.x * wd0.x + x0.y * wd0.y + x0.z * wd0.z + x0.w * wd0.w
            + x1.x * wd1.x + x1.y * wd1.y + x1.z * wd1.z + x1.w * wd1.w;
    for (int off = 32; off; off >>= 1) d += __shfl_xor(d, off, 64);
    d += bd;
    float g = 1.f / (1.f + __expf(-d));
    g0[it] = g;
    g1[it] = 1.f - g;
  }

  // ---- sq + colsum + combine ----
  float c0 = 0.f, c1 = 0.f, c2 = 0.f, c3 = 0.f;
  float bsq = 0.f;
#pragma unroll
  for (int it = 0; it < 8; ++it) {
    int m = blockIdx.x * 32 + wave * 8 + it;      // 0..4095
    bf16x4 v0 = *(const bf16x4*)(tot + tbidx(m, lane * 4));
    bf16x4 v1 = *(const bf16x4*)(tot + tbidx(4096 + m, lane * 4));
    float f00 = v0[0], f01 = v0[1], f02 = v0[2], f03 = v0[3];
    float f10 = v1[0], f11 = v1[1], f12 = v1[2], f13 = v1[3];
    float s0 = f00 * f00 + f01 * f01 + f02 * f02 + f03 * f03;
    float s1 = f10 * f10 + f11 * f11 + f12 * f12 + f13 * f13;
    for (int off = 32; off; off >>= 1) {
      s0 += __shfl_down(s0, off, 64);
      s1 += __shfl_down(s1, off, 64);
    }
    if (lane == 0) { sq[m] = s0; sq[4096 + m] = s1; bsq += s0 + s1; }
    c0 += f00 + f10; c1 += f01 + f11; c2 += f02 + f12; c3 += f03 + f13;
    float4 r;
    r.x = g0[it] * f00 + g1[it] * f10;
    r.y = g0[it] * f01 + g1[it] * f11;
    r.z = g0[it] * f02 + g1[it] * f12;
    r.w = g0[it] * f03 + g1[it] * f13;
    *(float4*)(out + (size_t)m * 256 + lane * 4) = r;
  }
  lcol[wave][lane * 4 + 0] = c0;
  lcol[wave][lane * 4 + 1] = c1;
  lcol[wave][lane * 4 + 2] = c2;
  lcol[wave][lane * 4 + 3] = c3;
  if (lane == 0) wsq[wave] = bsq;
  __syncthreads();
  float s2 = lcol[0][t] + lcol[1][t] + lcol[2][t] + lcol[3][t];
  atomicAdd(&colsum[t], s2);
  if (t == 0) atomicAdd(&scal[4], wsq[0] + wsq[1] + wsq[2] + wsq[3]);
  __threadfence();
  if (t == 0) {
    unsigned int c = atomicAdd((unsigned int*)(scal + 5), 1u);
    isLast = (c == 127u) ? 1u : 0u;
  }
  __syncthreads();
  if (isLast) {
    __threadfence();
    float cv = atomicAdd(&colsum[t], 0.0f);      // coherent read
    lcol[0][t] = cv * cv;
    __syncthreads();
    for (int off = 128; off; off >>= 1) {
      if (t < off) lcol[0][t] += lcol[0][t + off];
      __syncthreads();
    }
    if (t == 0) {
      float sumsq = atomicAdd(&scal[4], 0.0f);
      double sumdist = 2.0 * 8192.0 * (double)sumsq - 2.0 * (double)lcol[0][0];
      double bw = sumdist / (8192.0 * 8192.0 - 8192.0) / 4.0;  // / KERNEL_MUL^(5//2)
      scal[1] = (float)(1.4426950408889634 / (bw * 16.0));     // g4 * log2(e)
      scal[2] = (float)bw;
    }
  }
}

// ---------------- Gram tiles + fused multi-bandwidth kernel sum ---------------
// R15-proven (43.7 us — best of 7 structures tried across the session):
// 128x128 tiles, direct-fragment coalesced loads from fragment-major totalbf,
// explicit 2-deep even/odd register pipeline (VGPR ~100 holds acc[4][4] + two
// fragment sets), no LDS tiles, no barriers in the K-loop; triangular
// XCD-chunked grid (2080 = 8x260 bijective), fire-and-forget atomic with the
// final -S/2^24 scale folded in. UNCHANGED.
// (Falsified alternatives: LDS-dbuf 48, single-buf 72, counted-vmcnt 87,
//  row-major direct gather 102, 64x64 small-tile high-occupancy 112.)
__global__ __launch_bounds__(256) void k_gram(const __bf16* __restrict__ tot,
                                              const float* __restrict__ sq,
                                              const float* __restrict__ scal,
                                              float* __restrict__ out) {
  const int b = blockIdx.x;                    // 0..2079
  const int nid = (b & 7) * 260 + (b >> 3);    // XCD-chunked, bijective (2080=8*260)
  int ti = (int)((129.0 - sqrt(129.0 * 129.0 - 8.0 * (double)nid)) * 0.5);
  while (64 * ti - ti * (ti - 1) / 2 > nid) --ti;
  while (64 * (ti + 1) - (ti + 1) * ti / 2 <= nid) ++ti;
  const int tj = ti + (nid - (64 * ti - ti * (ti - 1) / 2));

  __shared__ float sqi[128], sqj[128];
  __shared__ float wred[4];
  const int t = threadIdx.x;
  const int wid = t >> 6, lane = t & 63;
  const int wr = wid >> 1, wc = wid & 1;
  const int n16 = lane & 15, q = lane >> 4;

  const float g = scal[1];           // log2e / (bw*16)
  if (t < 128) sqi[t] = sq[ti * 128 + t] * g;          // pre-scaled by g
  else         sqj[t - 128] = sq[tj * 128 + (t - 128)] * g;

  f32x4 acc[4][4];
  f32x4 zero = {0.f, 0.f, 0.f, 0.f};
  for (int i = 0; i < 4; ++i)
    for (int j = 0; j < 4; ++j) acc[i][j] = zero;

  // fragment bases: A-frag f covers rows ti*128+wr*64+f*16..+16 — row-block
  // (ti*8+wr*4+f); lane l's 16B slice at +l*8 elems; col-block ks at +ks*512.
  const __bf16* pA = tot + ((size_t)(ti * 8 + wr * 4) << 12) + lane * 8;
  const __bf16* pB = tot + ((size_t)(tj * 8 + wc * 4) << 12) + lane * 8;

  bf16x8 aE[4], bE[4], aO[4], bO[4];   // even/odd ks fragment sets
#pragma unroll
  for (int f = 0; f < 4; ++f) {
    aE[f] = *(const bf16x8*)(pA + ((size_t)f << 12));
    bE[f] = *(const bf16x8*)(pB + ((size_t)f << 12));
  }
#pragma unroll
  for (int ks = 0; ks < 8; ++ks) {
    // prefetch ks+1 into the other set (in flight during this ks's MFMAs)
    if (ks < 7) {
      if ((ks & 1) == 0) {
#pragma unroll
        for (int f = 0; f < 4; ++f) {
          aO[f] = *(const bf16x8*)(pA + ((size_t)f << 12) + ((size_t)(ks + 1) << 9));
          bO[f] = *(const bf16x8*)(pB + ((size_t)f << 12) + ((size_t)(ks + 1) << 9));
        }
      } else {
#pragma unroll
        for (int f = 0; f < 4; ++f) {
          aE[f] = *(const bf16x8*)(pA + ((size_t)f << 12) + ((size_t)(ks + 1) << 9));
          bE[f] = *(const bf16x8*)(pB + ((size_t)f << 12) + ((size_t)(ks + 1) << 9));
        }
      }
    }
    if ((ks & 1) == 0) {
      for (int fr = 0; fr < 4; ++fr)
        for (int fc = 0; fc < 4; ++fc)
          acc[fr][fc] = __builtin_amdgcn_mfma_f32_16x16x32_bf16(aE[fr], bE[fc], acc[fr][fc], 0, 0, 0);
    } else {
      for (int fr = 0; fr < 4; ++fr)
        for (int fc = 0; fc < 4; ++fc)
          acc[fr][fc] = __builtin_amdgcn_mfma_f32_16x16x32_bf16(aO[fr], bO[fc], acc[fr][fc], 0, 0, 0);
    }
  }

  __syncthreads();   // publish sqi/sqj (cross-wave)

  // epilogue: arg = 2g*acc - (g*si + g*sj); ksum = u+u2+u4+u8+u16, u=exp2(arg)
  const float twog = 2.f * g;
  float lsum = 0.f;
  for (int fr = 0; fr < 4; ++fr) {
    for (int r = 0; r < 4; ++r) {
      float gsi = sqi[wr * 64 + fr * 16 + q * 4 + r];
      for (int fc = 0; fc < 4; ++fc) {
        float gsj = sqj[wc * 64 + fc * 16 + n16];
        float u = exp2f(fmaf(twog, acc[fr][fc][r], -(gsi + gsj)));
        float u2 = u * u, u4 = u2 * u2, u8 = u4 * u4;
        float s1 = fmaf(u8, u8, u8);           // u16 + u8
        lsum += (u + u2) + (u4 + s1);
      }
    }
  }
  for (int off = 32; off; off >>= 1) lsum += __shfl_down(lsum, off, 64);
  if (lane == 0) wred[wid] = lsum;
  __syncthreads();
  if (t == 0) {
    float blocksum = wred[0] + wred[1] + wred[2] + wred[3];
    float sgn = ((ti < 32) == (tj < 32)) ? 1.f : -1.f;
    float wgt = (ti == tj) ? sgn : 2.f * sgn;
    // final scale folded in: out[1048576] = -S/2^24, accumulated directly
    atomicAdd(out + 1048576, wgt * blocksum * (-1.f / 16777216.f));
  }
}

extern "C" void kernel_launch(void* const* d_in, const int* in_sizes, int n_in,
                              void* d_out, int out_size, void* d_ws, size_t ws_size,
                              hipStream_t stream) {
  const float* x    = (const float*)d_in[0];
  const float* Waux = (const float*)d_in[1];
  const float* baux = (const float*)d_in[2];
  const float* W    = (const float*)d_in[3];
  const float* bias = (const float*)d_in[4];
  float* out = (float*)d_out;

  char* ws = (char*)d_ws;
  __bf16* totalbf = (__bf16*)ws;                    // 8192*256*2 = 4,194,304 B (tiled)
  float* sq      = (float*)(ws + 4194304);          // 8192 f32
  float* colsum  = (float*)(ws + 4227072);          // 256 f32
  float* scal    = (float*)(ws + 4228096);          // [1]=g4l2 [2]=bw [4]=sumsq [5]=cnt

  k_outs<<<dim3(16, 64), 256, 0, stream>>>(x, W, bias, totalbf, colsum, scal, out);
  k_sqc<<<128, 256, 0, stream>>>(totalbf, x, Waux, baux, sq, colsum, scal, out);
  k_gram<<<2080, 256, 0, stream>>>(totalbf, sq, scal, out);
}